// Round 1
// baseline (489.429 us; speedup 1.0000x reference)
//
#include <hip/hip_runtime.h>
#include <math.h>

#define B_ 2048
#define N_ 512
#define U_ 64

__global__ __launch_bounds__(256) void ntm_kernel(
    const float* __restrict__ memory,   // (B,N,U)
    const float* __restrict__ kk,       // (B,U)
    const float* __restrict__ beta_p,   // (1,)
    const float* __restrict__ g_p,      // (1,)
    const float* __restrict__ sv,       // (B,3)
    const float* __restrict__ gamma_p,  // (1,)
    const float* __restrict__ w_pre,    // (B,N)
    const float* __restrict__ ev,       // (B,U)
    const float* __restrict__ av,       // (B,U)
    float* __restrict__ out_w,          // (B,N)
    float* __restrict__ out_r,          // (B,U)
    float* __restrict__ out_m)          // (B,N,U)
{
    __shared__ float s_k[U_];
    __shared__ float s_sim[N_];     // sim, later reused to hold final w
    __shared__ float s_wg[N_];
    __shared__ float s_red[256];
    __shared__ float s_rred[4 * U_];
    __shared__ float s_ny;

    const int b    = blockIdx.x;
    const int tid  = threadIdx.x;
    const int wave = tid >> 6;
    const int lane = tid & 63;
    const int sub  = lane >> 4;      // 0..3 : which row within the wave
    const int l16  = lane & 15;      // 0..15: position within row group
    const int col  = l16 << 2;       // float4 column

    const float beta  = beta_p[0];
    const float g     = g_p[0];
    const float gamma = gamma_p[0];
    const float s0 = sv[b * 3 + 0], s1 = sv[b * 3 + 1], s2 = sv[b * 3 + 2];

    const size_t mem_base = (size_t)b * N_ * U_;

    // ---- key vector + its norm (wave 0 only) ----
    if (tid < U_) {
        float kx = kk[b * U_ + tid] + 1e-16f;
        s_k[tid] = kx;
        float v = kx * kx;
        #pragma unroll
        for (int off = 32; off; off >>= 1) v += __shfl_xor(v, off);
        if (tid == 0) s_ny = fmaxf(sqrtf(v), 1e-8f);
    }
    __syncthreads();
    const float ny = s_ny;

    // hoist loop-invariant k fragment
    const float k0 = s_k[col + 0], k1 = s_k[col + 1], k2 = s_k[col + 2], k3 = s_k[col + 3];

    // ---- pass 1: cosine similarity per row ----
    for (int n0 = 0; n0 < N_; n0 += 16) {
        const int n = n0 + (wave << 2) + sub;
        const float4 m4 = *(const float4*)(memory + mem_base + (size_t)n * U_ + col);
        const float x0 = m4.x + 1e-16f, x1 = m4.y + 1e-16f,
                    x2 = m4.z + 1e-16f, x3 = m4.w + 1e-16f;
        float dot = x0 * k0 + x1 * k1 + x2 * k2 + x3 * k3;
        float nsq = x0 * x0 + x1 * x1 + x2 * x2 + x3 * x3;
        #pragma unroll
        for (int off = 8; off; off >>= 1) {
            dot += __shfl_xor(dot, off);
            nsq += __shfl_xor(nsq, off);
        }
        if (l16 == 0) {
            const float nx = fmaxf(sqrtf(nsq), 1e-8f);
            s_sim[n] = dot / (nx * ny);
        }
    }
    __syncthreads();

    // ---- softmax(beta*sim) -> gate -> shift -> sharpen -> normalize ----
    const int i0 = tid, i1 = tid + 256;
    const float t0 = beta * s_sim[i0];
    const float t1 = beta * s_sim[i1];

    // max reduce
    s_red[tid] = fmaxf(t0, t1);
    __syncthreads();
    for (int ss = 128; ss > 0; ss >>= 1) {
        if (tid < ss) s_red[tid] = fmaxf(s_red[tid], s_red[tid + ss]);
        __syncthreads();
    }
    const float mx = s_red[0];
    __syncthreads();

    const float e0 = expf(t0 - mx);
    const float e1 = expf(t1 - mx);
    s_red[tid] = e0 + e1;
    __syncthreads();
    for (int ss = 128; ss > 0; ss >>= 1) {
        if (tid < ss) s_red[tid] += s_red[tid + ss];
        __syncthreads();
    }
    const float einv = 1.0f / s_red[0];
    __syncthreads();

    const float wp0 = w_pre[(size_t)b * N_ + i0];
    const float wp1 = w_pre[(size_t)b * N_ + i1];
    s_wg[i0] = g * (e0 * einv) + (1.0f - g) * wp0;
    s_wg[i1] = g * (e1 * einv) + (1.0f - g) * wp1;
    __syncthreads();

    // circular 3-tap shift: ws[n] = s0*wg[n-1] + s1*wg[n] + s2*wg[n+1]
    float wsv0, wsv1;
    {
        int nm = (i0 + N_ - 1) & (N_ - 1), np = (i0 + 1) & (N_ - 1);
        wsv0 = powf(s0 * s_wg[nm] + s1 * s_wg[i0] + s2 * s_wg[np], gamma);
        nm = (i1 + N_ - 1) & (N_ - 1); np = (i1 + 1) & (N_ - 1);
        wsv1 = powf(s0 * s_wg[nm] + s1 * s_wg[i1] + s2 * s_wg[np], gamma);
    }
    s_red[tid] = wsv0 + wsv1;
    __syncthreads();
    for (int ss = 128; ss > 0; ss >>= 1) {
        if (tid < ss) s_red[tid] += s_red[tid + ss];
        __syncthreads();
    }
    const float winv = 1.0f / s_red[0];
    __syncthreads();

    const float w0 = wsv0 * winv + 1e-16f;
    const float w1 = wsv1 * winv + 1e-16f;
    s_sim[i0] = w0;                       // reuse sim buffer as w
    s_sim[i1] = w1;
    out_w[(size_t)b * N_ + i0] = w0;
    out_w[(size_t)b * N_ + i1] = w1;
    __syncthreads();

    // ---- pass 2: read (r) + write (new_mem) ----
    const float4 e4 = *(const float4*)(ev + b * U_ + col);
    const float4 a4 = *(const float4*)(av + b * U_ + col);
    float rx = 0.f, ry = 0.f, rz = 0.f, rw = 0.f;

    for (int n0 = 0; n0 < N_; n0 += 16) {
        const int n = n0 + (wave << 2) + sub;
        const size_t off = mem_base + (size_t)n * U_ + col;
        const float4 m4 = *(const float4*)(memory + off);
        const float wn = s_sim[n];
        float4 o;
        o.x = m4.x * (1.0f - wn * e4.x) + wn * a4.x;
        o.y = m4.y * (1.0f - wn * e4.y) + wn * a4.y;
        o.z = m4.z * (1.0f - wn * e4.z) + wn * a4.z;
        o.w = m4.w * (1.0f - wn * e4.w) + wn * a4.w;
        *(float4*)(out_m + off) = o;
        rx += wn * m4.x; ry += wn * m4.y; rz += wn * m4.z; rw += wn * m4.w;
    }
    // reduce across the 4 row-subgroups of the wave (lanes l, l^16, l^32)
    rx += __shfl_xor(rx, 16); rx += __shfl_xor(rx, 32);
    ry += __shfl_xor(ry, 16); ry += __shfl_xor(ry, 32);
    rz += __shfl_xor(rz, 16); rz += __shfl_xor(rz, 32);
    rw += __shfl_xor(rw, 16); rw += __shfl_xor(rw, 32);
    if (lane < 16) {
        s_rred[wave * U_ + col + 0] = rx;
        s_rred[wave * U_ + col + 1] = ry;
        s_rred[wave * U_ + col + 2] = rz;
        s_rred[wave * U_ + col + 3] = rw;
    }
    __syncthreads();
    if (tid < U_) {
        const float rv = s_rred[tid] + s_rred[U_ + tid] + s_rred[2 * U_ + tid] + s_rred[3 * U_ + tid];
        out_r[(size_t)b * U_ + tid] = rv;
    }
}

extern "C" void kernel_launch(void* const* d_in, const int* in_sizes, int n_in,
                              void* d_out, int out_size, void* d_ws, size_t ws_size,
                              hipStream_t stream) {
    const float* memory = (const float*)d_in[0];
    const float* kk     = (const float*)d_in[1];
    const float* beta   = (const float*)d_in[2];
    const float* g      = (const float*)d_in[3];
    const float* sv     = (const float*)d_in[4];
    const float* gamma  = (const float*)d_in[5];
    const float* w_pre  = (const float*)d_in[6];
    const float* ev     = (const float*)d_in[7];
    const float* av     = (const float*)d_in[8];

    float* out   = (float*)d_out;
    float* out_w = out;                                        // B*N
    float* out_r = out + (size_t)B_ * N_;                      // B*U
    float* out_m = out + (size_t)B_ * N_ + (size_t)B_ * U_;    // B*N*U

    ntm_kernel<<<B_, 256, 0, stream>>>(memory, kk, beta, g, sv, gamma,
                                       w_pre, ev, av, out_w, out_r, out_m);
}